// Round 8
// baseline (217.758 us; speedup 1.0000x reference)
//
#include <hip/hip_runtime.h>

#define BB 16
#define HH 512
#define WW 512
#define BH 8
#define NR (BH+5)          // 13 rows incl. halo
#define NBANDS (HH/BH)     // 64
#define NBLK (NBANDS*BB)   // 1024
#define NREG 48
#define HWTOT (HH*WW)
#define MASK13 0x1FFFu

// ws layout (bytes):
//   0     float svvG[48]      576   int smdG[48]
//   192   int   svdG[48]      768   float rankvG[48]
//   384   float smvG[48]      960   int rankdG[48]
//   1152  int ctr (zeroed by pass1 block (0,0))
//   4096   float sumsP[1024][16]  ([li*4+s] E2 stats s=P,P2,dx,dy; [12]=sumAbs)
//   69632  int   countsP[1024][16] ([li*3+m]=cnt m=REG,E1,E2; [9+li]=cxE2; [12+li]=cyE2)
//   135168 int   rowcR[48][512]
//   233472 int   rowcE[48][512]
//   331776 u64   maskReg[48][512][8]
//   1904640 u64  maskE1 [48][512][8]
#define OFF_SVV   0
#define OFF_SVD   192
#define OFF_SMV   384
#define OFF_SMD   576
#define OFF_RANKV 768
#define OFF_RANKD 960
#define OFF_CTR   1152
#define OFF_SUMSP 4096
#define OFF_CNTP  (OFF_SUMSP + NBLK*16*4)
#define OFF_ROWCR (OFF_CNTP + NBLK*16*4)
#define OFF_ROWCE (OFF_ROWCR + 48*512*4)
#define OFF_MREG  (OFF_ROWCE + 48*512*4)
#define MASKBYTES (48LL*512*8*8)
#define OFF_ME1   (OFF_MREG + MASKBYTES)

__device__ __forceinline__ unsigned int hashu(unsigned int x) {
  x ^= x >> 16; x *= 0x7feb352dU; x ^= x >> 15; x *= 0x846ca68bU; x ^= x >> 16;
  return x;
}

__global__ __launch_bounds__(512, 4) void pass1_kernel(
    const float* __restrict__ pred, const float* __restrict__ target,
    const int* __restrict__ lab,
    float* __restrict__ sumsP, int* __restrict__ countsP,
    unsigned long long* __restrict__ mRegG, unsigned long long* __restrict__ mE1G,
    int* __restrict__ rowcR, int* __restrict__ rowcE,
    int* __restrict__ ctr)
{
  __shared__ unsigned long long XCH[514];   // packed 3x13-bit column masks
  __shared__ unsigned int NBX[512];         // E2 neighbor windows (3x8 bits)
  __shared__ int   RC[48];                  // rowcnt [type(2)][li(3)][row(8)]
  __shared__ float RED[8][13];
  __shared__ unsigned int CNT[8][8];

  const int t    = threadIdx.x;
  const int lane = t & 63;
  const int wv   = t >> 6;
  const int c    = t;
  const int r0   = blockIdx.x * BH;
  const int b    = blockIdx.y;
  const int R    = r0 - 3;
  const int blk  = b * NBANDS + blockIdx.x;

  if (blockIdx.x == 0 && b == 0 && t == 0) *ctr = 0;
  if (t < 48) RC[t] = 0;

  // out-of-image rows; erosion treats them as inside (clipped SAME)
  unsigned int OOR = 0;
  {
    int topClip = -R;
    if (topClip > 0) OOR |= (1u << topClip) - 1u;
    int botStart = HH - R;
    if (botStart < NR) OOR |= (~0u << botStart) & ((1u << NR) - 1u);
  }

  // ---- per-column label masks (13 bits) ----
  unsigned int colm0 = 0, colm1 = 0, colm2 = 0;
  #pragma unroll
  for (int lr = 0; lr < NR; ++lr) {
    int gy = R + lr;
    if ((unsigned)gy < (unsigned)HH) {
      int l = lab[((size_t)b*HH + gy)*WW + c];
      colm0 |= (l == 5)  ? (1u << lr) : 0u;
      colm1 |= (l == 8)  ? (1u << lr) : 0u;
      colm2 |= (l == 13) ? (1u << lr) : 0u;
    }
  }

  // ---- erosion 1 ----
  unsigned long long pk =  (unsigned long long)(colm0 | OOR)
        | ((unsigned long long)(colm1 | OOR) << 13)
        | ((unsigned long long)(colm2 | OOR) << 26);
  XCH[c+1] = pk;
  if (t == 0) { XCH[0] = ~0ull; XCH[513] = ~0ull; }
  __syncthreads();
  unsigned long long hp = pk & XCH[c] & XCH[c+2];
  unsigned int e1a[3];
  #pragma unroll
  for (int li = 0; li < 3; ++li) {
    unsigned int h = (unsigned int)((hp >> (13*li)) & MASK13);
    e1a[li] = h & (h >> 1) & (h << 1);     // valid lr 1..11
  }
  __syncthreads();
  // ---- erosion 2 ----
  unsigned long long pk2 =  (unsigned long long)((e1a[0] | OOR) & MASK13)
        | ((unsigned long long)((e1a[1] | OOR) & MASK13) << 13)
        | ((unsigned long long)((e1a[2] | OOR) & MASK13) << 26);
  XCH[c+1] = pk2;
  __syncthreads();
  unsigned long long hp2 = pk2 & XCH[c] & XCH[c+2];
  unsigned int e2a[3];
  #pragma unroll
  for (int li = 0; li < 3; ++li) {
    unsigned int h = (unsigned int)((hp2 >> (13*li)) & MASK13);
    e2a[li] = h & (h >> 1) & (h << 1);     // valid lr 2..10
  }

  // combo order cb = li*3 + m, m: 0=REG 1=E1 2=E2
  unsigned int mS[9] = { colm0, e1a[0], e2a[0],
                         colm1, e1a[1], e2a[1],
                         colm2, e1a[2], e2a[2] };

  // ---- E2 neighbor exchange (stats need hpairs for E2 only) ----
  NBX[c] =  ((e2a[0] >> 3) & 0xFFu)
         | (((e2a[1] >> 3) & 0xFFu) << 8)
         | (((e2a[2] >> 3) & 0xFFu) << 16);
  __syncthreads();
  unsigned int nbx = (c < 511) ? NBX[c+1] : 0u;

  // ---- packed E2 windows: W2[li] = cell8 | hpair8<<8 | vpair8<<16 ----
  unsigned int W2[3];
  const unsigned int nOOR = ~OOR;
  #pragma unroll
  for (int li = 0; li < 3; ++li) {
    unsigned int w8  = (e2a[li] >> 3) & 0xFFu;
    unsigned int nbw = (nbx >> (8*li)) & 0xFFu;
    unsigned int mcl = e2a[li] & nOOR;
    unsigned int py8 = ((mcl & (mcl << 1)) >> 3) & 0xFFu;
    W2[li] = w8 | ((w8 & nbw) << 8) | (py8 << 16);
  }

  // ---- 48 ballots -> lanes, one scatter store per wave + rowcounts ----
  {
    unsigned long long w1 = 0;
    #pragma unroll
    for (int k = 0; k < 48; ++k) {
      const int ktype = k / 24, krem = k % 24, kli = krem >> 3, krow = krem & 7;
      unsigned int bit = (mS[kli*3 + ktype] >> (krow + 3)) & 1u;
      unsigned long long wrd = __ballot(bit != 0u);
      if (lane == k) w1 = wrd;
    }
    if (lane < 48) {
      int type = lane / 24, rem = lane % 24, li = rem >> 3, row = rem & 7;
      unsigned long long* dst = type ? mE1G : mRegG;
      dst[(((size_t)(b*3 + li))*HH + (r0 + row))*8 + wv] = w1;
      atomicAdd(&RC[lane], (int)__popcll(w1));
    }
  }

  // ---- counts: cnt for 9 combos + cx,cy for E2; 15x16-bit in 8 u32 ----
  {
    unsigned int v15[15];
    #pragma unroll
    for (int cb = 0; cb < 9; ++cb) v15[cb] = __popc((mS[cb] >> 3) & 0xFFu);
    #pragma unroll
    for (int li = 0; li < 3; ++li) {
      v15[9+li]  = __popc(W2[li] & 0x00FF00u);
      v15[12+li] = __popc(W2[li] & 0xFF0000u);
    }
    unsigned int pkc[8];
    #pragma unroll
    for (int j = 0; j < 7; ++j) pkc[j] = v15[2*j] | (v15[2*j+1] << 16);
    pkc[7] = v15[14];
    #pragma unroll
    for (int j = 0; j < 8; ++j) {
      unsigned int v = pkc[j];
      for (int off = 32; off; off >>= 1) v += __shfl_down(v, off);
      if (lane == 0) CNT[wv][j] = v;
    }
  }

  // ---- stats row loop: E2 only (3 combos) ----
  float aP[3] = {}, aP2[3] = {}, aDX[3] = {}, aDY[3] = {};
  float aAbs = 0.f;
  const float* pB = pred   + (size_t)b*HH*WW;
  const float* tB = target + (size_t)b*HH*WW;
  float p_prev = (r0 > 0) ? pB[(size_t)(r0-1)*WW + c] : 0.f;
  const int cR = (c < 511) ? c + 1 : c;

  #pragma unroll
  for (int row = 0; row < BH; ++row) {
    const int gy = r0 + row;
    const float* prow = pB + (size_t)gy*WW;
    float p  = prow[c];
    float pr = prow[cR];
    float tg = tB[(size_t)gy*WW + c];
    aAbs += fabsf(p - tg);
    float d = fabsf(pr - p);
    float v = fabsf(p - p_prev);
    #pragma unroll
    for (int li = 0; li < 3; ++li) {
      unsigned int c1 = (W2[li] >> row) & 1u;
      unsigned int px = (W2[li] >> (row + 8)) & 1u;
      unsigned int py = (W2[li] >> (row + 16)) & 1u;
      float f = c1 ? p : 0.f;
      aP[li]  += f;
      aP2[li]  = fmaf(f, p, aP2[li]);
      aDX[li] += px ? d : 0.f;
      aDY[li] += py ? v : 0.f;
    }
    p_prev = p;
  }

  // ---- wave reduce 13 floats -> LDS ----
  {
    float a13[13] = { aP[0], aP2[0], aDX[0], aDY[0],
                      aP[1], aP2[1], aDX[1], aDY[1],
                      aP[2], aP2[2], aDX[2], aDY[2], aAbs };
    #pragma unroll
    for (int j = 0; j < 13; ++j) {
      float s = a13[j];
      for (int off = 32; off; off >>= 1) s += __shfl_down(s, off);
      if (lane == 0) RED[wv][j] = s;
    }
  }
  __syncthreads();

  // ---- per-block partial outputs (plain stores) ----
  if (t < 13) {
    float s = 0.f;
    #pragma unroll
    for (int w = 0; w < 8; ++w) s += RED[w][t];
    sumsP[(size_t)blk*16 + t] = s;
  }
  if (t < 8) {
    unsigned int s = 0;
    #pragma unroll
    for (int w = 0; w < 8; ++w) s += CNT[w][t];
    countsP[blk*16 + 2*t] = (int)(s & 0xFFFFu);
    if (2*t + 1 < 15) countsP[blk*16 + 2*t + 1] = (int)(s >> 16);
  }
  if (t < 48) {
    int type = t / 24, rem = t % 24, li = rem >> 3, row = rem & 7;
    int* dst = type ? rowcE : rowcR;
    dst[((size_t)(b*3 + li))*HH + (r0 + row)] = RC[t];
  }
}

__global__ __launch_bounds__(256) void pass2_kernel(
    const float* __restrict__ pred, const float* __restrict__ img1,
    const float* __restrict__ img2,
    const unsigned long long* __restrict__ mRegG,
    const unsigned long long* __restrict__ mE1G,
    const float* __restrict__ sumsP, const int* __restrict__ countsP,
    const int* __restrict__ rowcR, const int* __restrict__ rowcE,
    float* __restrict__ svvG, int* __restrict__ svdG,
    float* __restrict__ smvG, int* __restrict__ smdG,
    float* __restrict__ rankvG, int* __restrict__ rankdG,
    int* __restrict__ ctr, float* __restrict__ out)
{
  const int r = blockIdx.x;       // 0..47
  const int b = r / 3, li = r % 3;
  const int t = threadIdx.x;
  const int lane = t & 63;
  const int wv   = t >> 6;
  __shared__ int rcR[HH], rcE[HH];
  __shared__ int pre[HH];
  __shared__ int grpPre[64];
  __shared__ int LC[5];          // n_reg, n_e1, n_e2, cxE2, cyE2
  __shared__ float SP[4];        // reduced E2 sums P,P2,dx,dy
  __shared__ float FBf[4][4];
  __shared__ int   FBi[4][2];
  __shared__ int idxArr[200];
  __shared__ float redH[4];
  __shared__ int   redP[4];
  __shared__ int lastFlag;
  __shared__ double svvS[NREG], smvS[NREG];
  __shared__ int svdS[NREG], smdS[NREG];
  __shared__ float rkvS[NREG];
  __shared__ int   rkdS[NREG];
  __shared__ double SAB[4];

  if (t < 5) LC[t] = 0;
  // rowc load (coalesced int2)
  int2 vR = ((const int2*)(rowcR + (size_t)r*HH))[t];
  int2 vE = ((const int2*)(rowcE + (size_t)r*HH))[t];
  rcR[2*t] = vR.x; rcR[2*t+1] = vR.y;
  rcE[2*t] = vE.x; rcE[2*t+1] = vE.y;
  __syncthreads();

  // counts reduce: 5 values x 64 bands
  for (int k = t; k < 5*NBANDS; k += 256) {
    int s5 = k >> 6, band = k & 63;
    int j = (s5 < 3) ? (li*3 + s5) : ((s5 == 3) ? (9 + li) : (12 + li));
    atomicAdd(&LC[s5], countsP[(b*NBANDS + band)*16 + j]);
  }
  // E2 sums reduce: wave 0, lane = band
  if (wv == 0) {
    float sp[4];
    #pragma unroll
    for (int s = 0; s < 4; ++s)
      sp[s] = sumsP[(size_t)(b*NBANDS + lane)*16 + li*4 + s];
    #pragma unroll
    for (int s = 0; s < 4; ++s)
      for (int off = 32; off; off >>= 1) sp[s] += __shfl_down(sp[s], off);
    if (lane == 0) { SP[0]=sp[0]; SP[1]=sp[1]; SP[2]=sp[2]; SP[3]=sp[3]; }
  }
  __syncthreads();

  const int n_reg = LC[0], n_e1 = LC[1], n_e2 = LC[2];
  const int m1 = (n_e1 < 2) ? 0 : 1;
  const int m2 = (n_e2 < 3) ? m1 : 2;

  // ---- fallback: m2 != 2 (rare) -> recompute stats from stored masks ----
  float fP = 0.f, fP2 = 0.f, fDX = 0.f, fDY = 0.f;
  int fCX = 0, fCY = 0;
  if (m2 != 2) {
    const unsigned long long* M2 = ((m2 == 1) ? mE1G : mRegG) + (size_t)r*HH*8;
    const float* pB = pred + (size_t)b*HWTOT;
    #pragma unroll
    for (int rr = 0; rr < 2; ++rr) {
      int row = t + rr*256;
      const unsigned long long* mrow = M2 + (size_t)row*8;
      const float* prow = pB + (size_t)row*WW;
      for (int w = 0; w < 8; ++w) {
        unsigned long long mm = mrow[w];
        unsigned long long cc = mm;
        while (cc) {
          int i = __builtin_ctzll(cc); cc &= cc - 1;
          float p = prow[w*64 + i];
          fP += p; fP2 = fmaf(p, p, fP2);
        }
        unsigned long long nxt = (w < 7) ? mrow[w+1] : 0ull;
        unsigned long long pm = mm & ((mm >> 1) | (nxt << 63));
        while (pm) {
          int i = __builtin_ctzll(pm); pm &= pm - 1;
          fDX += fabsf(prow[w*64 + i + 1] - prow[w*64 + i]); fCX++;
        }
        if (row > 0) {
          unsigned long long qm = mm & mrow[w - 8];
          while (qm) {
            int i = __builtin_ctzll(qm); qm &= qm - 1;
            fDY += fabsf(prow[w*64 + i] - prow[w*64 + i - WW]); fCY++;
          }
        }
      }
    }
  }
  {
    float s0=fP, s1=fP2, s2=fDX, s3=fDY; int i0=fCX, i1=fCY;
    for (int off = 32; off; off >>= 1) {
      s0 += __shfl_down(s0, off); s1 += __shfl_down(s1, off);
      s2 += __shfl_down(s2, off); s3 += __shfl_down(s3, off);
      i0 += __shfl_down(i0, off); i1 += __shfl_down(i1, off);
    }
    if (lane == 0) {
      FBf[wv][0]=s0; FBf[wv][1]=s1; FBf[wv][2]=s2; FBf[wv][3]=s3;
      FBi[wv][0]=i0; FBi[wv][1]=i1;
    }
  }

  // ---- rank sampling (bit-identical to prior rounds) ----
  int useE1 = (n_e1 >= 2);
  int n1 = useE1 ? n_e1 : n_reg;
  bool doRank = (n_reg >= 2 && n1 >= 2);
  float rv = 0.f; int rvd = 0;

  if (doRank) {
    const int* rc = useE1 ? rcE : rcR;
    if (t < 64) {
      int base = t*8, s = 0;
      #pragma unroll
      for (int k = 0; k < 8; ++k) s += rc[base + k];
      int v = s;
      for (int off = 1; off < 64; off <<= 1) {
        int o = __shfl_up(v, off);
        if (t >= off) v += o;
      }
      grpPre[t] = v - s;
    }
    __syncthreads();
    if (t < 64) {
      int s = grpPre[t], base = t*8;
      #pragma unroll
      for (int k = 0; k < 8; ++k) { pre[base + k] = s; s += rc[base + k]; }
    }
    __syncthreads();

    const unsigned long long* M = (useE1 ? mE1G : mRegG) + (size_t)r*HH*8;
    if (t < 200) {
      unsigned int h = hashu(0x9e3779b9u + (unsigned)(r*200 + t));
      float u = (float)(h >> 8) * (1.0f / 16777216.0f);
      int k = (int)(u * (float)n1);
      if (k >= n1) k = n1 - 1;
      if (k < 0) k = 0;
      int lo = 0, hi = HH;
      while (hi - lo > 1) { int mid = (lo + hi) >> 1; if (pre[mid] <= k) lo = mid; else hi = mid; }
      int row = lo;
      int local = k - pre[row];
      int idx = 0;
      #pragma unroll
      for (int w = 0; w < 8; ++w) {
        unsigned long long mm = M[(size_t)row*8 + w];
        int cc = __popcll(mm);
        if (local < cc) {
          for (int i = 0; i < local; ++i) mm &= mm - 1;
          idx = row*WW + w*64 + __builtin_ctzll(mm);
          local = 1 << 20;
        } else {
          local -= cc;
        }
      }
      idxArr[t] = idx;
    }
    __syncthreads();

    float hv = 0.f; int pv = 0;
    if (t < 100) {
      int ii = idxArr[t], jj = idxArr[t+100];
      size_t base = (size_t)b * HWTOT;
      float pi = pred[base+ii], pj = pred[base+jj];
      float xi = 0.5f*(1.f - img1[base+ii]) + 0.5f*img2[base+ii];
      float xj = 0.5f*(1.f - img1[base+jj]) + 0.5f*img2[base+jj];
      float s = (xi > xj) ? 1.f : ((xi < xj) ? -1.f : 0.f);
      pv = (ii != jj) && (s != 0.f);
      float hinge = fmaxf(0.f, -(pi - pj)*s);
      hv = pv ? hinge : 0.f;
    }
    for (int off = 32; off; off >>= 1) {
      hv += __shfl_down(hv, off);
      pv += __shfl_down(pv, off);
    }
    if (lane == 0) { redH[wv] = hv; redP[wv] = pv; }
  }
  __syncthreads();

  // ---- region results + arrival (t==0) ----
  if (t == 0) {
    if (doRank) {
      float sh = redH[0] + redH[1] + redH[2] + redH[3];
      int   sp = redP[0] + redP[1] + redP[2] + redP[3];
      rv  = sh / (float)(sp > 0 ? sp : 1);
      rvd = (sp > 0) ? 1 : 0;
    }
    double S0, S1, S2, S3; int n2, cx, cy;
    if (m2 == 2) {
      S0 = SP[0]; S1 = SP[1]; S2 = SP[2]; S3 = SP[3];
      n2 = n_e2; cx = LC[3]; cy = LC[4];
    } else {
      S0 = (double)(FBf[0][0]+FBf[1][0]+FBf[2][0]+FBf[3][0]);
      S1 = (double)(FBf[0][1]+FBf[1][1]+FBf[2][1]+FBf[3][1]);
      S2 = (double)(FBf[0][2]+FBf[1][2]+FBf[2][2]+FBf[3][2]);
      S3 = (double)(FBf[0][3]+FBf[1][3]+FBf[2][3]+FBf[3][3]);
      n2 = (m2 == 1) ? n_e1 : n_reg;
      cx = FBi[0][0]+FBi[1][0]+FBi[2][0]+FBi[3][0];
      cy = FBi[0][1]+FBi[1][1]+FBi[2][1]+FBi[3][1];
    }
    double n2s = (double)(n2 > 1 ? n2 : 1);
    double mu  = S0 / n2s;
    double var = S1 / n2s - mu*mu;
    if (var < 0.0) var = 0.0;
    double cv = sqrt(var) / (fabs(mu) + 1e-6);
    double tcv = (li == 0) ? 0.077 : ((li == 1) ? 0.227 : 0.348);
    double mean_x = S2 / (double)(cx > 1 ? cx : 1);
    double mean_y = S3 / (double)(cy > 1 ? cy : 1);
    int hx = (cx > 0), hy = (cy > 0);
    int npres = hx + hy;
    atomicExch(&svvG[r], (float)fabs(cv - tcv));
    atomicExch(&svdG[r], (int)(n_reg >= 3 && n2 >= 3));
    atomicExch(&smvG[r], (float)((mean_x*hx + mean_y*hy) / (double)(npres > 1 ? npres : 1)));
    atomicExch(&smdG[r], (int)(n_reg >= 3 && n2 >= 3 && npres > 0));
    atomicExch(&rankvG[r], rv);
    atomicExch(&rankdG[r], rvd);
    __threadfence();
    int old = atomicAdd(ctr, 1);
    lastFlag = (old == NREG - 1);
  }
  __syncthreads();

  // ---- last block: global combine ----
  if (lastFlag) {
    __threadfence();   // acquire
    double pa = 0.0;
    for (int k = t; k < NBLK; k += 256) pa += (double)sumsP[(size_t)k*16 + 12];
    for (int off = 32; off; off >>= 1) pa += __shfl_down(pa, off);
    if (lane == 0) SAB[wv] = pa;
    if (t < NREG) {
      svvS[t] = (double)svvG[t]; svdS[t] = svdG[t];
      smvS[t] = (double)smvG[t]; smdS[t] = smdG[t];
      rkvS[t] = rankvG[t];       rkdS[t] = rankdG[t];
    }
    __syncthreads();
    if (t == 0) {
      double s_std = 0, s_sm = 0, s_rk = 0;
      int c_std = 0, c_sm = 0, c_rk = 0;
      for (int i = 0; i < NREG; ++i) {
        if (svdS[i]) { s_std += svvS[i]; c_std++; }
        if (smdS[i]) { s_sm  += smvS[i]; c_sm++;  }
        if (rkdS[i]) { s_rk  += (double)rkvS[i]; c_rk++; }
      }
      double loss_std = c_std ? s_std / c_std : 0.0;
      double loss_sm  = c_sm  ? s_sm  / c_sm  : 0.0;
      double loss_rk  = c_rk  ? s_rk  / c_rk  : 0.0;
      double loss_mean = (SAB[0] + SAB[1] + SAB[2] + SAB[3])
                         / (double)((long long)BB * HWTOT);
      out[0] = (float)(0.5*loss_mean + 0.5*loss_std + loss_rk + loss_sm);
    }
  }
}

extern "C" void kernel_launch(void* const* d_in, const int* in_sizes, int n_in,
                              void* d_out, int out_size, void* d_ws, size_t ws_size,
                              hipStream_t stream) {
  const float* pred   = (const float*)d_in[0];
  const float* target = (const float*)d_in[1];
  const int*   lab    = (const int*)d_in[2];
  const float* img1   = (const float*)d_in[3];
  const float* img2   = (const float*)d_in[4];
  float* out = (float*)d_out;
  char* ws = (char*)d_ws;

  float* svvG   = (float*)(ws + OFF_SVV);
  int*   svdG   = (int*)(ws + OFF_SVD);
  float* smvG   = (float*)(ws + OFF_SMV);
  int*   smdG   = (int*)(ws + OFF_SMD);
  float* rankvG = (float*)(ws + OFF_RANKV);
  int*   rankdG = (int*)(ws + OFF_RANKD);
  int*   ctr    = (int*)(ws + OFF_CTR);
  float* sumsP  = (float*)(ws + OFF_SUMSP);
  int*   countsP= (int*)(ws + OFF_CNTP);
  int*   rowcR  = (int*)(ws + OFF_ROWCR);
  int*   rowcE  = (int*)(ws + OFF_ROWCE);
  unsigned long long* mReg = (unsigned long long*)(ws + OFF_MREG);
  unsigned long long* mE1  = (unsigned long long*)(ws + OFF_ME1);

  dim3 g1(NBANDS, BB);
  pass1_kernel<<<g1, 512, 0, stream>>>(pred, target, lab, sumsP, countsP,
                                       mReg, mE1, rowcR, rowcE, ctr);
  pass2_kernel<<<NREG, 256, 0, stream>>>(pred, img1, img2, mReg, mE1,
                                         sumsP, countsP, rowcR, rowcE,
                                         svvG, svdG, smvG, smdG,
                                         rankvG, rankdG, ctr, out);
}